// Round 1
// baseline (2143.226 us; speedup 1.0000x reference)
//
#include <hip/hip_runtime.h>
#include <math.h>

#define NN 500000
#define NE 5000000

// ---------------- layer 1: din=3 ----------------

__global__ __launch_bounds__(256) void proj1_kernel(
    const float* __restrict__ x, const float* __restrict__ w,
    const float* __restrict__ b, float* __restrict__ h, int n)
{
    int i = blockIdx.x * 256 + threadIdx.x;
    if (i >= n) return;
    float x0 = x[i*3+0], x1 = x[i*3+1], x2 = x[i*3+2];
#pragma unroll
    for (int j = 0; j < 3; ++j) {
        float v = fmaf(x0, w[0*3+j], fmaf(x1, w[1*3+j], fmaf(x2, w[2*3+j], b[j])));
        h[i*3+j] = v > 0.f ? v : 0.f;
    }
}

__global__ __launch_bounds__(256) void scatter3_kernel(
    const int* __restrict__ ei, const float* __restrict__ h,
    float* __restrict__ agg, int e_count)
{
    int e = blockIdx.x * 256 + threadIdx.x;
    if (e >= e_count) return;
    int s = ei[e];
    int d = ei[e_count + e];
    float v0 = h[s*3+0], v1 = h[s*3+1], v2 = h[s*3+2];
    atomicAdd(&agg[d*3+0], v0);
    atomicAdd(&agg[d*3+1], v1);
    atomicAdd(&agg[d*3+2], v2);
}

__global__ __launch_bounds__(256) void combine1_kernel(
    const float* __restrict__ agg, const float* __restrict__ x,
    const float* __restrict__ lw, const float* __restrict__ lb,
    const float* __restrict__ rw, float* __restrict__ out, int n)
{
    int i = blockIdx.x * 256 + threadIdx.x;
    if (i >= n) return;
    float a0 = agg[i*3+0], a1 = agg[i*3+1], a2 = agg[i*3+2];
    float x0 = x[i*3+0], x1 = x[i*3+1], x2 = x[i*3+2];
    float4* op = reinterpret_cast<float4*>(out + (size_t)i * 16);
#pragma unroll
    for (int q = 0; q < 4; ++q) {
        float4 o;
        float* ov = &o.x;
#pragma unroll
        for (int jj = 0; jj < 4; ++jj) {
            int j = q * 4 + jj;
            float v = lb[j];
            v = fmaf(a0, lw[0*16+j], v);
            v = fmaf(a1, lw[1*16+j], v);
            v = fmaf(a2, lw[2*16+j], v);
            v = fmaf(x0, rw[0*16+j], v);
            v = fmaf(x1, rw[1*16+j], v);
            v = fmaf(x2, rw[2*16+j], v);
            ov[jj] = v > 0.f ? v : 0.f;
        }
        op[q] = o;
    }
}

// ---------------- layer 2: 16 -> 16 ----------------

__global__ __launch_bounds__(256) void proj16_kernel(
    const float* __restrict__ x, const float* __restrict__ w,
    const float* __restrict__ b, float* __restrict__ h, int n)
{
    __shared__ float sw[256];
    __shared__ float sb[16];
    sw[threadIdx.x] = w[threadIdx.x];
    if (threadIdx.x < 16) sb[threadIdx.x] = b[threadIdx.x];
    __syncthreads();
    int i = blockIdx.x * 256 + threadIdx.x;
    if (i >= n) return;
    float xv[16];
    const float4* xp = reinterpret_cast<const float4*>(x + (size_t)i * 16);
#pragma unroll
    for (int q = 0; q < 4; ++q) {
        float4 t = xp[q];
        xv[q*4+0] = t.x; xv[q*4+1] = t.y; xv[q*4+2] = t.z; xv[q*4+3] = t.w;
    }
    float4* hp = reinterpret_cast<float4*>(h + (size_t)i * 16);
#pragma unroll
    for (int q = 0; q < 4; ++q) {
        float4 o;
        float* ov = &o.x;
#pragma unroll
        for (int jj = 0; jj < 4; ++jj) {
            int j = q * 4 + jj;
            float v = sb[j];
#pragma unroll
            for (int k = 0; k < 16; ++k) v = fmaf(xv[k], sw[k*16+j], v);
            ov[jj] = v > 0.f ? v : 0.f;
        }
        hp[q] = o;
    }
}

__global__ __launch_bounds__(256) void scatter16_kernel(
    const int* __restrict__ ei, const float* __restrict__ h,
    float* __restrict__ agg, int e_count)
{
    int tid = blockIdx.x * 256 + threadIdx.x;
    int e = tid >> 2;
    int q = tid & 3;
    if (e >= e_count) return;
    int s = ei[e];
    int d = ei[e_count + e];
    float4 v = *reinterpret_cast<const float4*>(h + (size_t)s * 16 + q * 4);
    float* ap = agg + (size_t)d * 16 + q * 4;
    atomicAdd(ap + 0, v.x);
    atomicAdd(ap + 1, v.y);
    atomicAdd(ap + 2, v.z);
    atomicAdd(ap + 3, v.w);
}

__global__ __launch_bounds__(256) void combine2_kernel(
    const float* __restrict__ agg, const float* __restrict__ xr,
    const float* __restrict__ lw, const float* __restrict__ lb,
    const float* __restrict__ rw, float* __restrict__ out, int n)
{
    __shared__ float slw[256];
    __shared__ float srw[256];
    __shared__ float slb[16];
    slw[threadIdx.x] = lw[threadIdx.x];
    srw[threadIdx.x] = rw[threadIdx.x];
    if (threadIdx.x < 16) slb[threadIdx.x] = lb[threadIdx.x];
    __syncthreads();
    int i = blockIdx.x * 256 + threadIdx.x;
    if (i >= n) return;
    float av[16], xv[16];
    const float4* ap = reinterpret_cast<const float4*>(agg + (size_t)i * 16);
    const float4* xp = reinterpret_cast<const float4*>(xr + (size_t)i * 16);
#pragma unroll
    for (int q = 0; q < 4; ++q) {
        float4 t = ap[q];
        av[q*4+0] = t.x; av[q*4+1] = t.y; av[q*4+2] = t.z; av[q*4+3] = t.w;
        float4 u = xp[q];
        xv[q*4+0] = u.x; xv[q*4+1] = u.y; xv[q*4+2] = u.z; xv[q*4+3] = u.w;
    }
    float4* op = reinterpret_cast<float4*>(out + (size_t)i * 16);
#pragma unroll
    for (int q = 0; q < 4; ++q) {
        float4 o;
        float* ov = &o.x;
#pragma unroll
        for (int jj = 0; jj < 4; ++jj) {
            int j = q * 4 + jj;
            float v = slb[j];
#pragma unroll
            for (int k = 0; k < 16; ++k) v = fmaf(av[k], slw[k*16+j], v);
#pragma unroll
            for (int k = 0; k < 16; ++k) v = fmaf(xv[k], srw[k*16+j], v);
            ov[jj] = v > 0.f ? v : 0.f;
        }
        op[q] = o;
    }
}

// ---------------- layer 3: 16 -> 1, pre-apply l3w so scatter is scalar ----------------

__global__ __launch_bounds__(256) void layer3_node_kernel(
    const float* __restrict__ x, const float* __restrict__ pw,
    const float* __restrict__ pb, const float* __restrict__ lw,
    float* __restrict__ g, int n)
{
    __shared__ float spw[256];
    __shared__ float spb[16];
    __shared__ float slw[16];
    spw[threadIdx.x] = pw[threadIdx.x];
    if (threadIdx.x < 16) {
        spb[threadIdx.x] = pb[threadIdx.x];
        slw[threadIdx.x] = lw[threadIdx.x];
    }
    __syncthreads();
    int i = blockIdx.x * 256 + threadIdx.x;
    if (i >= n) return;
    float xv[16];
    const float4* xp = reinterpret_cast<const float4*>(x + (size_t)i * 16);
#pragma unroll
    for (int q = 0; q < 4; ++q) {
        float4 t = xp[q];
        xv[q*4+0] = t.x; xv[q*4+1] = t.y; xv[q*4+2] = t.z; xv[q*4+3] = t.w;
    }
    float acc = 0.f;
#pragma unroll
    for (int j = 0; j < 16; ++j) {
        float v = spb[j];
#pragma unroll
        for (int k = 0; k < 16; ++k) v = fmaf(xv[k], spw[k*16+j], v);
        v = v > 0.f ? v : 0.f;
        acc = fmaf(v, slw[j], acc);
    }
    g[i] = acc;
}

__global__ __launch_bounds__(256) void scatterS_kernel(
    const int* __restrict__ ei, const float* __restrict__ g,
    float* __restrict__ agg, int e_count)
{
    int e = blockIdx.x * 256 + threadIdx.x;
    if (e >= e_count) return;
    int s = ei[e];
    int d = ei[e_count + e];
    atomicAdd(&agg[d], g[s]);
}

__global__ __launch_bounds__(256) void combine3_kernel(
    const float* __restrict__ agg, const float* __restrict__ x,
    const float* __restrict__ lb, const float* __restrict__ rw,
    float* __restrict__ out, int n)
{
    int i = blockIdx.x * 256 + threadIdx.x;
    if (i >= n) return;
    float xv[16];
    const float4* xp = reinterpret_cast<const float4*>(x + (size_t)i * 16);
#pragma unroll
    for (int q = 0; q < 4; ++q) {
        float4 t = xp[q];
        xv[q*4+0] = t.x; xv[q*4+1] = t.y; xv[q*4+2] = t.z; xv[q*4+3] = t.w;
    }
    float v = agg[i] + lb[0];
#pragma unroll
    for (int k = 0; k < 16; ++k) v = fmaf(xv[k], rw[k], v);
    out[i] = 1.f / (1.f + expf(-v));
}

extern "C" void kernel_launch(void* const* d_in, const int* in_sizes, int n_in,
                              void* d_out, int out_size, void* d_ws, size_t ws_size,
                              hipStream_t stream) {
    const float* x   = (const float*)d_in[0];
    const int*   ei  = (const int*)d_in[1];
    const float* p1w = (const float*)d_in[2];
    const float* p1b = (const float*)d_in[3];
    const float* l1w = (const float*)d_in[4];
    const float* l1b = (const float*)d_in[5];
    const float* r1w = (const float*)d_in[6];
    const float* p2w = (const float*)d_in[7];
    const float* p2b = (const float*)d_in[8];
    const float* l2w = (const float*)d_in[9];
    const float* l2b = (const float*)d_in[10];
    const float* r2w = (const float*)d_in[11];
    const float* p3w = (const float*)d_in[12];
    const float* p3b = (const float*)d_in[13];
    const float* l3w = (const float*)d_in[14];
    const float* l3b = (const float*)d_in[15];
    const float* r3w = (const float*)d_in[16];
    float* out = (float*)d_out;

    char* ws = (char*)d_ws;
    const size_t BUF = (size_t)NN * 16 * sizeof(float);  // 32 MB
    float* buf0 = (float*)(ws);            // h (per layer), then out2
    float* buf1 = (float*)(ws + BUF);      // agg (zeroed each layer)
    float* buf2 = (float*)(ws + 2 * BUF);  // out1, then g3

    const int N = NN, E = NE;
    const int nbN = (N + 255) / 256;
    const int nbE = (E + 255) / 256;

    // ---- layer 1 ----
    proj1_kernel<<<nbN, 256, 0, stream>>>(x, p1w, p1b, buf0, N);
    hipMemsetAsync(buf1, 0, (size_t)N * 3 * sizeof(float), stream);
    scatter3_kernel<<<nbE, 256, 0, stream>>>(ei, buf0, buf1, E);
    combine1_kernel<<<nbN, 256, 0, stream>>>(buf1, x, l1w, l1b, r1w, buf2, N);

    // ---- layer 2 ----
    proj16_kernel<<<nbN, 256, 0, stream>>>(buf2, p2w, p2b, buf0, N);
    hipMemsetAsync(buf1, 0, (size_t)N * 16 * sizeof(float), stream);
    scatter16_kernel<<<(E * 4 + 255) / 256, 256, 0, stream>>>(ei, buf0, buf1, E);
    combine2_kernel<<<nbN, 256, 0, stream>>>(buf1, buf2, l2w, l2b, r2w, buf0, N);

    // ---- layer 3 ----
    layer3_node_kernel<<<nbN, 256, 0, stream>>>(buf0, p3w, p3b, l3w, buf2, N);
    hipMemsetAsync(buf1, 0, (size_t)N * sizeof(float), stream);
    scatterS_kernel<<<nbE, 256, 0, stream>>>(ei, buf2, buf1, E);
    combine3_kernel<<<nbN, 256, 0, stream>>>(buf1, buf0, l3b, r3w, out, N);
}

// Round 2
// 693.961 us; speedup vs baseline: 3.0884x; 3.0884x over previous
//
#include <hip/hip_runtime.h>
#include <math.h>

#define NN 500000
#define NE 5000000
#define SC_CH 2048                          // elements per scan block (256 thr * 8)
#define NB_SC ((NN + SC_CH - 1) / SC_CH)    // 245 (fits in one 256-thread block)

// ================= CSR build =================

__global__ __launch_bounds__(256) void hist_kernel(
    const int* __restrict__ ei, int* __restrict__ counter, int* __restrict__ rank)
{
    int e = blockIdx.x * 256 + threadIdx.x;
    if (e >= NE) return;
    int d = ei[NE + e];
    rank[e] = atomicAdd(&counter[d], 1);
}

__global__ __launch_bounds__(256) void scan_reduce_kernel(
    const int* __restrict__ cnt, int* __restrict__ partial)
{
    __shared__ int sm[256];
    int base = blockIdx.x * SC_CH + threadIdx.x * 8;
    int s = 0;
#pragma unroll
    for (int k = 0; k < 8; ++k) { int i = base + k; if (i < NN) s += cnt[i]; }
    sm[threadIdx.x] = s;
    __syncthreads();
    for (int off = 128; off > 0; off >>= 1) {
        if (threadIdx.x < off) sm[threadIdx.x] += sm[threadIdx.x + off];
        __syncthreads();
    }
    if (threadIdx.x == 0) partial[blockIdx.x] = sm[0];
}

__global__ __launch_bounds__(256) void scan_mid_kernel(int* __restrict__ partial)
{
    __shared__ int sm[256];
    int t = threadIdx.x;
    int orig = (t < NB_SC) ? partial[t] : 0;
    sm[t] = orig;
    __syncthreads();
    for (int off = 1; off < 256; off <<= 1) {
        int v = (t >= off) ? sm[t - off] : 0;
        __syncthreads();
        sm[t] += v;
        __syncthreads();
    }
    if (t < NB_SC) partial[t] = sm[t] - orig;   // exclusive
}

__global__ __launch_bounds__(256) void scan_apply_kernel(
    const int* __restrict__ cnt, const int* __restrict__ partial, int* __restrict__ rowptr)
{
    __shared__ int sm[256];
    int b = blockIdx.x, t = threadIdx.x;
    int base = b * SC_CH + t * 8;
    int v[8]; int s = 0;
#pragma unroll
    for (int k = 0; k < 8; ++k) { int i = base + k; v[k] = (i < NN) ? cnt[i] : 0; s += v[k]; }
    sm[t] = s;
    __syncthreads();
    int orig = s;
    for (int off = 1; off < 256; off <<= 1) {
        int u = (t >= off) ? sm[t - off] : 0;
        __syncthreads();
        sm[t] += u;
        __syncthreads();
    }
    int run = partial[b] + sm[t] - orig;
#pragma unroll
    for (int k = 0; k < 8; ++k) { int i = base + k; if (i < NN) rowptr[i] = run; run += v[k]; }
    if (b == 0 && t == 0) rowptr[NN] = NE;
}

__global__ __launch_bounds__(256) void fill_kernel(
    const int* __restrict__ ei, const int* __restrict__ rowptr,
    const int* __restrict__ rank, int* __restrict__ csr_src)
{
    int e = blockIdx.x * 256 + threadIdx.x;
    if (e >= NE) return;
    int s = ei[e];
    int d = ei[NE + e];
    csr_src[rowptr[d] + rank[e]] = s;
}

// ================= layer 1: din=3 =================

__global__ __launch_bounds__(256) void proj1_kernel(
    const float* __restrict__ x, const float* __restrict__ w,
    const float* __restrict__ b, float* __restrict__ h)
{
    int i = blockIdx.x * 256 + threadIdx.x;
    if (i >= NN) return;
    float x0 = x[i*3+0], x1 = x[i*3+1], x2 = x[i*3+2];
#pragma unroll
    for (int j = 0; j < 3; ++j) {
        float v = fmaf(x0, w[0*3+j], fmaf(x1, w[1*3+j], fmaf(x2, w[2*3+j], b[j])));
        h[i*3+j] = v > 0.f ? v : 0.f;
    }
}

__global__ __launch_bounds__(256) void fuse1_kernel(
    const int* __restrict__ rowptr, const int* __restrict__ csr_src,
    const float* __restrict__ h1, const float* __restrict__ x,
    const float* __restrict__ lw, const float* __restrict__ lb,
    const float* __restrict__ rw, float* out)
{
    int i = blockIdx.x * 256 + threadIdx.x;
    if (i >= NN) return;
    int beg = rowptr[i], end = rowptr[i+1];
    float a0 = 0.f, a1 = 0.f, a2 = 0.f;
    for (int e = beg; e < end; ++e) {
        int s = csr_src[e];
        a0 += h1[s*3+0]; a1 += h1[s*3+1]; a2 += h1[s*3+2];
    }
    float x0 = x[i*3+0], x1 = x[i*3+1], x2 = x[i*3+2];
    float4* op = reinterpret_cast<float4*>(out + (size_t)i * 16);
#pragma unroll
    for (int q = 0; q < 4; ++q) {
        float4 o;
        float* ov = &o.x;
#pragma unroll
        for (int jj = 0; jj < 4; ++jj) {
            int j = q * 4 + jj;
            float v = lb[j];
            v = fmaf(a0, lw[0*16+j], v);
            v = fmaf(a1, lw[1*16+j], v);
            v = fmaf(a2, lw[2*16+j], v);
            v = fmaf(x0, rw[0*16+j], v);
            v = fmaf(x1, rw[1*16+j], v);
            v = fmaf(x2, rw[2*16+j], v);
            ov[jj] = v > 0.f ? v : 0.f;
        }
        op[q] = o;
    }
}

// ================= layer 2: 16 -> 16 =================

__global__ __launch_bounds__(256) void proj16_kernel(
    const float* __restrict__ x, const float* __restrict__ w,
    const float* __restrict__ b, float* __restrict__ h)
{
    __shared__ float sw[256];
    __shared__ float sb[16];
    sw[threadIdx.x] = w[threadIdx.x];
    if (threadIdx.x < 16) sb[threadIdx.x] = b[threadIdx.x];
    __syncthreads();
    int i = blockIdx.x * 256 + threadIdx.x;
    if (i >= NN) return;
    float xv[16];
    const float4* xp = reinterpret_cast<const float4*>(x + (size_t)i * 16);
#pragma unroll
    for (int q = 0; q < 4; ++q) {
        float4 t = xp[q];
        xv[q*4+0] = t.x; xv[q*4+1] = t.y; xv[q*4+2] = t.z; xv[q*4+3] = t.w;
    }
    float4* hp = reinterpret_cast<float4*>(h + (size_t)i * 16);
#pragma unroll
    for (int q = 0; q < 4; ++q) {
        float4 o;
        float* ov = &o.x;
#pragma unroll
        for (int jj = 0; jj < 4; ++jj) {
            int j = q * 4 + jj;
            float v = sb[j];
#pragma unroll
            for (int k = 0; k < 16; ++k) v = fmaf(xv[k], sw[k*16+j], v);
            ov[jj] = v > 0.f ? v : 0.f;
        }
        hp[q] = o;
    }
}

// 4 threads per node; gather float4 quads, LDS transpose, fused combine.
// out may alias xr (in-place): each node's xr is read only by its own quad
// before the __syncthreads; written after. No __restrict__ on xr/out.
__global__ __launch_bounds__(256) void fuse2_kernel(
    const int* __restrict__ rowptr, const int* __restrict__ csr_src,
    const float* __restrict__ h, const float* xr,
    const float* __restrict__ lw, const float* __restrict__ lb,
    const float* __restrict__ rw, float* out)
{
    __shared__ float slw[256];
    __shared__ float srw[256];
    __shared__ float slb[16];
    __shared__ float sagg[64][17];
    __shared__ float sx[64][17];
    slw[threadIdx.x] = lw[threadIdx.x];
    srw[threadIdx.x] = rw[threadIdx.x];
    if (threadIdx.x < 16) slb[threadIdx.x] = lb[threadIdx.x];

    int tid  = blockIdx.x * 256 + threadIdx.x;
    int node = tid >> 2;
    int q    = tid & 3;
    int l    = threadIdx.x >> 2;
    bool act = node < NN;

    if (act) {
        int beg = rowptr[node], end = rowptr[node+1];
        float4 acc = make_float4(0.f, 0.f, 0.f, 0.f);
        for (int e = beg; e < end; ++e) {
            int s = csr_src[e];
            float4 v = *reinterpret_cast<const float4*>(h + (size_t)s * 16 + q * 4);
            acc.x += v.x; acc.y += v.y; acc.z += v.z; acc.w += v.w;
        }
        float4 xv = *reinterpret_cast<const float4*>(xr + (size_t)node * 16 + q * 4);
        sagg[l][q*4+0] = acc.x; sagg[l][q*4+1] = acc.y;
        sagg[l][q*4+2] = acc.z; sagg[l][q*4+3] = acc.w;
        sx[l][q*4+0] = xv.x; sx[l][q*4+1] = xv.y;
        sx[l][q*4+2] = xv.z; sx[l][q*4+3] = xv.w;
    }
    __syncthreads();
    if (act) {
        float av[16], xv[16];
#pragma unroll
        for (int k = 0; k < 16; ++k) { av[k] = sagg[l][k]; xv[k] = sx[l][k]; }
        float4 o;
        float* ov = &o.x;
#pragma unroll
        for (int jj = 0; jj < 4; ++jj) {
            int j = q * 4 + jj;
            float v = slb[j];
#pragma unroll
            for (int k = 0; k < 16; ++k) v = fmaf(av[k], slw[k*16+j], v);
#pragma unroll
            for (int k = 0; k < 16; ++k) v = fmaf(xv[k], srw[k*16+j], v);
            ov[jj] = v > 0.f ? v : 0.f;
        }
        *reinterpret_cast<float4*>(out + (size_t)node * 16 + q * 4) = o;
    }
}

// ================= layer 3: 16 -> 1 =================

__global__ __launch_bounds__(256) void node3_kernel(
    const float* __restrict__ x, const float* __restrict__ pw,
    const float* __restrict__ pb, const float* __restrict__ lw,
    float* __restrict__ g)
{
    __shared__ float spw[256];
    __shared__ float spb[16];
    __shared__ float slw[16];
    spw[threadIdx.x] = pw[threadIdx.x];
    if (threadIdx.x < 16) {
        spb[threadIdx.x] = pb[threadIdx.x];
        slw[threadIdx.x] = lw[threadIdx.x];
    }
    __syncthreads();
    int i = blockIdx.x * 256 + threadIdx.x;
    if (i >= NN) return;
    float xv[16];
    const float4* xp = reinterpret_cast<const float4*>(x + (size_t)i * 16);
#pragma unroll
    for (int q = 0; q < 4; ++q) {
        float4 t = xp[q];
        xv[q*4+0] = t.x; xv[q*4+1] = t.y; xv[q*4+2] = t.z; xv[q*4+3] = t.w;
    }
    float acc = 0.f;
#pragma unroll
    for (int j = 0; j < 16; ++j) {
        float v = spb[j];
#pragma unroll
        for (int k = 0; k < 16; ++k) v = fmaf(xv[k], spw[k*16+j], v);
        v = v > 0.f ? v : 0.f;
        acc = fmaf(v, slw[j], acc);
    }
    g[i] = acc;
}

__global__ __launch_bounds__(256) void fuse3_kernel(
    const int* __restrict__ rowptr, const int* __restrict__ csr_src,
    const float* __restrict__ g, const float* __restrict__ xr,
    const float* __restrict__ lb, const float* __restrict__ rw,
    float* __restrict__ out)
{
    int i = blockIdx.x * 256 + threadIdx.x;
    if (i >= NN) return;
    int beg = rowptr[i], end = rowptr[i+1];
    float a = 0.f;
    for (int e = beg; e < end; ++e) a += g[csr_src[e]];
    float xv[16];
    const float4* xp = reinterpret_cast<const float4*>(xr + (size_t)i * 16);
#pragma unroll
    for (int q = 0; q < 4; ++q) {
        float4 t = xp[q];
        xv[q*4+0] = t.x; xv[q*4+1] = t.y; xv[q*4+2] = t.z; xv[q*4+3] = t.w;
    }
    float v = a + lb[0];
#pragma unroll
    for (int k = 0; k < 16; ++k) v = fmaf(xv[k], rw[k], v);
    out[i] = 1.f / (1.f + expf(-v));
}

// ================= launch =================

extern "C" void kernel_launch(void* const* d_in, const int* in_sizes, int n_in,
                              void* d_out, int out_size, void* d_ws, size_t ws_size,
                              hipStream_t stream) {
    const float* x   = (const float*)d_in[0];
    const int*   ei  = (const int*)d_in[1];
    const float* p1w = (const float*)d_in[2];
    const float* p1b = (const float*)d_in[3];
    const float* l1w = (const float*)d_in[4];
    const float* l1b = (const float*)d_in[5];
    const float* r1w = (const float*)d_in[6];
    const float* p2w = (const float*)d_in[7];
    const float* p2b = (const float*)d_in[8];
    const float* l2w = (const float*)d_in[9];
    const float* l2b = (const float*)d_in[10];
    const float* r2w = (const float*)d_in[11];
    const float* p3w = (const float*)d_in[12];
    const float* p3b = (const float*)d_in[13];
    const float* l3w = (const float*)d_in[14];
    const float* l3b = (const float*)d_in[15];
    const float* r3w = (const float*)d_in[16];
    float* out = (float*)d_out;

    char* ws = (char*)d_ws;
    const size_t MB = 1024 * 1024;
    // B region [0,32MB): rank during build, then x2/x3 (in-place)
    // A region [32,64MB): counter during build, then h1 / h2 / g
    float* bufB    = (float*)(ws);
    int*   rank    = (int*)(ws);
    float* bufA    = (float*)(ws + 32 * MB);
    int*   counter = (int*)(ws + 32 * MB);
    int*   rowptr  = (int*)(ws + 64 * MB);          // (NN+1) ints
    int*   csr_src = (int*)(ws + 66 * MB);          // NE ints (20 MB)
    int*   partial = (int*)(ws + 86 * MB);          // NB_SC ints

    const int nbN = (NN + 255) / 256;
    const int nbE = (NE + 255) / 256;

    // ---- CSR build (reused by all 3 layers) ----
    hipMemsetAsync(counter, 0, (size_t)NN * sizeof(int), stream);
    hist_kernel<<<nbE, 256, 0, stream>>>(ei, counter, rank);
    scan_reduce_kernel<<<NB_SC, 256, 0, stream>>>(counter, partial);
    scan_mid_kernel<<<1, 256, 0, stream>>>(partial);
    scan_apply_kernel<<<NB_SC, 256, 0, stream>>>(counter, partial, rowptr);
    fill_kernel<<<nbE, 256, 0, stream>>>(ei, rowptr, rank, csr_src);

    // ---- layer 1 ----  (h1 in A overwrites dead counter; x2 in B overwrites dead rank)
    proj1_kernel<<<nbN, 256, 0, stream>>>(x, p1w, p1b, bufA);
    fuse1_kernel<<<nbN, 256, 0, stream>>>(rowptr, csr_src, bufA, x, l1w, l1b, r1w, bufB);

    // ---- layer 2 ----  (h2 in A; x3 written in-place over x2 in B)
    proj16_kernel<<<nbN, 256, 0, stream>>>(bufB, p2w, p2b, bufA);
    fuse2_kernel<<<(NN * 4 + 255) / 256, 256, 0, stream>>>(rowptr, csr_src, bufA, bufB,
                                                           l2w, l2b, r2w, bufB);

    // ---- layer 3 ----  (g in A)
    node3_kernel<<<nbN, 256, 0, stream>>>(bufB, p3w, p3b, l3w, bufA);
    fuse3_kernel<<<nbN, 256, 0, stream>>>(rowptr, csr_src, bufA, bufB, l3b, r3w, out);
}